// Round 10
// baseline (74.396 us; speedup 1.0000x reference)
//
#include <hip/hip_runtime.h>
#include <hip/hip_bf16.h>

// Problem constants (from setup_inputs): B=4, N=8192, M=8192, D=3, fp32.
constexpr int B = 4;
constexpr int N = 8192;
constexpr int M = 8192;

constexpr int QPW     = 128;           // queries per wave (4 B-fragments)
constexpr int WAVES   = 4;             // waves per block
constexpr int QB      = QPW * WAVES;   // 512 queries per block
constexpr int QTILES  = N / QB;        // 16
constexpr int PCHUNKS = 16;            // point split -> grid 1024 = 4 blocks/CU
constexpr int CHUNK   = M / PCHUNKS;   // 512 points per block
constexpr int PTILES  = CHUNK / 32;    // 16 A-tile loads, 64 mfmas per wave

typedef __bf16 bf16x8 __attribute__((ext_vector_type(8)));
typedef float  f32x16 __attribute__((ext_vector_type(16)));

union FragU { uint4 u; bf16x8 b; };

// fp32 -> bf16 bits, round-to-nearest-even (finite inputs only).
__device__ inline unsigned f2bf(float x) {
    unsigned u = __float_as_uint(x);
    return (u + 0x7FFFu + ((u >> 16) & 1u)) >> 16;
}
__device__ inline float bf2f(unsigned b) { return __uint_as_float(b << 16); }
__device__ inline unsigned pk(unsigned lo, unsigned hi) { return lo | (hi << 16); }

// ---------------------------------------------------------------------------
// K-slot packing (mfma_f32_32x32x16_bf16, A rows = points, B cols = queries):
//   k0..3 : A=(ph0,ph0,pl0,pl0)  B=(ah0,al0,ah0,al0)  -> (ph0+pl0)(ah0+al0)
//   k4..7 : dim 1   k8..11: dim 2   k12,13: A=(sh,sl) B=(1,1) -> ||p||^2
//   k14,15: 0         (p' = -2p, everything split bf16 hi/lo)
// acc[row=point][col=query] = -2 a.p + ||p||^2  (validated R7/R8: absmax
// 7.8e-3 vs 6.75e-2 threshold).
// A-frag layout: A[m=lane&31][k=(lane>>5)*8+j] -> two 16B halves per point.
// ---------------------------------------------------------------------------

// Prep: pack each point's two A-fragment halves into wtab (32 B/point, 1 MB)
// AND initialize out to 0x7F7F7F7F (3.39e38f; uint order == float order for
// non-negative floats, so atomicMin(uint) implements float min). B*M == B*N.
__global__ __launch_bounds__(256) void prep_kernel(const float* __restrict__ point,
                                                   uint4* __restrict__ wtab,
                                                   unsigned int* __restrict__ out) {
    int i = blockIdx.x * 256 + threadIdx.x;   // 0 .. B*M-1
    if (i >= B * M) return;
    const float p0 = point[3 * i + 0];
    const float p1 = point[3 * i + 1];
    const float p2 = point[3 * i + 2];
    const float v0 = -2.0f * p0, v1 = -2.0f * p1, v2 = -2.0f * p2;
    const unsigned h0 = f2bf(v0), l0 = f2bf(v0 - bf2f(h0));
    const unsigned h1 = f2bf(v1), l1 = f2bf(v1 - bf2f(h1));
    const unsigned h2 = f2bf(v2), l2 = f2bf(v2 - bf2f(h2));
    const float s = fmaf(p0, p0, fmaf(p1, p1, p2 * p2));
    const unsigned sh = f2bf(s), sl = f2bf(s - bf2f(sh));
    uint4 f0, f1;
    f0.x = pk(h0, h0); f0.y = pk(l0, l0); f0.z = pk(h1, h1); f0.w = pk(l1, l1); // k0..7
    f1.x = pk(h2, h2); f1.y = pk(l2, l2); f1.z = pk(sh, sl); f1.w = 0;          // k8..15
    wtab[2 * i + 0] = f0;
    wtab[2 * i + 1] = f1;
    out[i] = 0x7F7F7F7Fu;
}

// Build the B fragment for query index q (this lane's column).
__device__ inline FragU make_bfrag(const float* __restrict__ input,
                                   int b, int q, int h, float& sq_a) {
    const float* a = input + ((size_t)b * N + q) * 3;
    const float a0 = a[0], a1 = a[1], a2 = a[2];
    sq_a = fmaf(a0, a0, fmaf(a1, a1, a2 * a2));
    const unsigned ah0 = f2bf(a0), al0 = f2bf(a0 - bf2f(ah0));
    const unsigned ah1 = f2bf(a1), al1 = f2bf(a1 - bf2f(ah1));
    const unsigned ah2 = f2bf(a2), al2 = f2bf(a2 - bf2f(ah2));
    FragU bq;
    const unsigned dA = h ? pk(ah2, al2) : pk(ah0, al0);
    const unsigned dB = h ? 0x3F803F80u  : pk(ah1, al1);   // (1,1) bf16 | dim1
    bq.u.x = dA;
    bq.u.y = dA;
    bq.u.z = dB;
    bq.u.w = h ? 0u : dB;
    return bq;
}

// Main: one wave = 128 queries (4 B frags) vs its 512-point chunk.
// Per 2 A-tile loads: 8 mfmas + 64 v_min3 (8/mfma, pairing the two A-tiles
// per B-frag). Each A load feeds 4 mfmas -> VMEM instructions halved vs R8.
__global__ __launch_bounds__(256, 3) void main_kernel(const float* __restrict__ input,
                                                      const uint4* __restrict__ wtab,
                                                      unsigned int* __restrict__ out) {
    const int bid    = blockIdx.x;
    const int pchunk = bid % PCHUNKS;
    const int qtile  = (bid / PCHUNKS) % QTILES;
    const int b      = bid / (PCHUNKS * QTILES);
    const int tid    = threadIdx.x;
    const int wave   = tid >> 6;
    const int lane   = tid & 63;
    const int col    = lane & 31;          // A: point row in tile; B: query col
    const int h      = lane >> 5;          // k-half

    const int qbase = qtile * QB + wave * QPW + col;
    FragU bq[4];
    float sq_a[4];
#pragma unroll
    for (int j = 0; j < 4; ++j)
        bq[j] = make_bfrag(input, b, qbase + 32 * j, h, sq_a[j]);

    const uint4* __restrict__ wp =
        wtab + ((size_t)b * M + (size_t)pchunk * CHUNK) * 2;

    f32x16 cz, rmin[4];
#pragma unroll
    for (int i = 0; i < 16; ++i) {
        cz[i] = 0.0f;
        rmin[0][i] = 1e30f; rmin[1][i] = 1e30f;
        rmin[2][i] = 1e30f; rmin[3][i] = 1e30f;
    }

    for (int t = 0; t < PTILES; t += 2) {
        FragU fa0, fa1;
        fa0.u = wp[((t * 32 + col) << 1) + h];
        fa1.u = wp[(((t + 1) * 32 + col) << 1) + h];
#pragma unroll
        for (int j = 0; j < 4; ++j) {
            f32x16 acc0 = __builtin_amdgcn_mfma_f32_32x32x16_bf16(fa0.b, bq[j].b, cz, 0, 0, 0);
            f32x16 acc1 = __builtin_amdgcn_mfma_f32_32x32x16_bf16(fa1.b, bq[j].b, cz, 0, 0, 0);
#pragma unroll
            for (int i = 0; i < 16; ++i)
                rmin[j][i] = fminf(rmin[j][i], fminf(acc0[i], acc1[i]));  // v_min3_f32
        }
    }

    // Epilogue: in-lane fold (16 rows) + cross-half shuffle + atomic merge.
#pragma unroll
    for (int j = 0; j < 4; ++j) {
        float m = rmin[j][0];
#pragma unroll
        for (int i = 1; i < 16; ++i) m = fminf(m, rmin[j][i]);
        m = fminf(m, __shfl_xor(m, 32, 64));
        if (lane < 32) {
            const float d2 = fmaxf(m + sq_a[j], 0.0f);
            atomicMin(&out[(size_t)b * N + qbase + 32 * j], __float_as_uint(d2));
        }
    }
}

extern "C" void kernel_launch(void* const* d_in, const int* in_sizes, int n_in,
                              void* d_out, int out_size, void* d_ws, size_t ws_size,
                              hipStream_t stream) {
    const float* input = (const float*)d_in[0];   // [B, N, 3] fp32
    const float* point = (const float*)d_in[1];   // [B, M, 3] fp32
    unsigned int* out  = (unsigned int*)d_out;    // [B, N] fp32 viewed as uint

    uint4* wtab = (uint4*)d_ws;                   // 1 MB packed A-fragment table

    const int prep_grid = (B * M + 255) / 256;        // 128 blocks
    const int main_grid = B * QTILES * PCHUNKS;       // 1024 blocks

    prep_kernel<<<prep_grid, 256, 0, stream>>>(point, wtab, out);
    main_kernel<<<main_grid, 256, 0, stream>>>(input, wtab, out);
}